// Round 11
// baseline (362.463 us; speedup 1.0000x reference)
//
#include <hip/hip_runtime.h>
#include <hip/hip_fp16.h>
#include <math.h>

#define GHH 224
#define GWW 224
#define HW (GHH*GWW)     // 50176
#define BATCH 8
#define RAD 3
#define DIAM 7
#define NPTS 49
#define QC 32
#define TILE 16
#define TP (TILE + 2*RAD)   // 22
#define TPIX (TP*TP)        // 484
#define SHP 2112            // q-compute round scratch plane stride (bytes)
// smem carve (bytes): qpm 500px*64 = 32000 | sh 484*16 = 7744 | scr 4*4640 = 18560
#define QPM_B 32000
#define SH_B  7744
#define SCR_W 4640          // per-wave scratch stride
#define SCR_R 1160          // per-row stride inside wave scratch (8-aligned, bank-offset vs 1152)
#define SCR_N 72            // per-center-px stride (16 j * 72 = 1152)

typedef _Float16 v8h __attribute__((ext_vector_type(8)));
typedef float v4f __attribute__((ext_vector_type(4)));

__device__ __forceinline__ int refl(int i) {
    if (i < 0) i = -i;
    if (i >= GHH) i = 2 * GHH - 2 - i;
    return i;
}

__device__ __forceinline__ float gelu_fast(float v) {
    float u = 0.7978845608f * v * (1.f + 0.044715f * v * v);
    float e = __expf(2.f * u);
    float th = 1.f - 2.f / (e + 1.f);
    return 0.5f * v * (1.f + th);
}

// ---------------- linear (+ fused w2 B-frag prep in extra block) ----------------
__global__ void linear_prep_kernel(const float* __restrict__ x,
                                   const float* __restrict__ W,
                                   const float* __restrict__ bias,
                                   float* __restrict__ f0,
                                   const float* __restrict__ w2s,
                                   __half* __restrict__ wsB) {
    if (blockIdx.x == 1944) {   // prep: pack w2 (4 stages) into f16 MFMA B-fragments
        int tid = threadIdx.x;  // 256 = 4 stages x 64 lanes
        int s = tid >> 6, l = tid & 63;
        int n0 = l & 15, kq = l >> 4;
        const float* w2 = w2s + s * 1024;
        __half* dst = wsB + (size_t)tid * 16;
        #pragma unroll
        for (int j = 0; j < 8; j++) {
            dst[j]     = __float2half(w2[n0 * QC + kq * 8 + j]);
            dst[8 + j] = __float2half(w2[(n0 + 16) * QC + kq * 8 + j]);
        }
        return;
    }
    int gwave = (blockIdx.x * blockDim.x + threadIdx.x) >> 6;
    int lane = threadIdx.x & 63;
    if (gwave >= BATCH * 972) return;
    int b = gwave / 972, j = gwave % 972;
    const float* xr = x + b * 1000;
    const float* wr = W + j * 1000;
    float s = 0.f;
    for (int k = lane; k < 1000; k += 64)
        s += xr[k] * wr[k];
    #pragma unroll
    for (int off = 32; off; off >>= 1) s += __shfl_down(s, off, 64);
    if (lane == 0) f0[gwave] = s + bias[j];
}

// ---------------- bicubic 18 -> 224 ----------------
__device__ __forceinline__ float cubicw(float d) {
    d = fabsf(d);
    if (d <= 1.f) return ((1.25f * d - 2.25f) * d) * d + 1.f;
    if (d < 2.f)  return ((-0.75f * d + 3.75f) * d - 6.f) * d + 3.f;
    return 0.f;
}

__global__ void bicubic_kernel(const float* __restrict__ f0, float* __restrict__ hr) {
    int idx = blockIdx.x * blockDim.x + threadIdx.x;
    if (idx >= BATCH * 3 * HW) return;
    int w = idx % GWW;
    int h = (idx / GWW) % GHH;
    int bc = idx / HW;
    const float* src = f0 + bc * 18 * 18;
    float xx = (w + 0.5f) * (18.f / 224.f) - 0.5f;
    float yy = (h + 0.5f) * (18.f / 224.f) - 0.5f;
    float fx0 = floorf(xx), fy0 = floorf(yy);
    int x0 = (int)fx0, y0 = (int)fy0;
    float tx = xx - fx0, ty = yy - fy0;
    float wx[4], wy[4];
    int ix[4], iy[4];
    #pragma unroll
    for (int k = 0; k < 4; k++) {
        wx[k] = cubicw(tx - (float)(k - 1));
        wy[k] = cubicw(ty - (float)(k - 1));
        int a = x0 + (k - 1); ix[k] = min(max(a, 0), 17);
        a = y0 + (k - 1);     iy[k] = min(max(a, 0), 17);
    }
    float acc = 0.f;
    #pragma unroll
    for (int ky = 0; ky < 4; ky++) {
        float rowv = 0.f;
        #pragma unroll
        for (int kx = 0; kx < 4; kx++) rowv += wx[kx] * src[iy[ky] * 18 + ix[kx]];
        acc += wy[ky] * rowv;
    }
    hr[idx] = acc;
}

// ---------------- fully fused JBU: q-compute (MFMA) + MFMA scores + softmax + conv ----------------
__global__ __launch_bounds__(256, 2) void jbu_kernel(
    const float* __restrict__ guid,
    const float* __restrict__ w1, const float* __restrict__ b1,
    const __half* __restrict__ wsB, const float* __restrict__ b2,
    const float* __restrict__ hr,
    float* __restrict__ outF,
    const float* __restrict__ temps,
    const float* __restrict__ sigmas,
    int stage)
{
    __shared__ __align__(16) char smem[QPM_B + SH_B + 4 * SCR_W];  // 58304 B
    char*   qpm = smem;                         // q tile, pixel-major f16 [500 px][64 B]
    float4* sh  = (float4*)(smem + QPM_B);      // hr tile (3ch + pad)
    char*   scr = smem + QPM_B + SH_B;          // wave-private score scratch / q-round scratch

    const int tx = threadIdx.x, ty = threadIdx.y;
    const int tid = ty * TILE + tx;
    const int b = blockIdx.z;
    const int h0 = blockIdx.y * TILE, w0 = blockIdx.x * TILE;

    // ---- stage hr tile ----
    const bool interior = (h0 >= RAD) && (h0 + TILE + RAD <= GHH) &&
                          (w0 >= RAD) && (w0 + TILE + RAD <= GWW);
    if (interior) {
        const float* hb = hr + (size_t)b * 3 * HW + (size_t)(h0 - RAD) * GWW + (w0 - RAD);
        for (int i = tid; i < TPIX; i += 256) {
            int r = i / TP, cx = i % TP;
            size_t base = (size_t)r * GWW + cx;
            sh[i] = make_float4(hb[base], hb[base + HW], hb[base + 2 * HW], 0.f);
        }
    } else {
        for (int i = tid; i < TPIX; i += 256) {
            int r = i / TP, cx = i % TP;
            int gh = refl(h0 - RAD + r);
            int gw = refl(w0 - RAD + cx);
            size_t base = (size_t)b * 3 * HW + (size_t)gh * GWW + gw;
            sh[i] = make_float4(hr[base], hr[base + HW], hr[base + 2 * HW], 0.f);
        }
    }

    // ---- phase 0: q tile (layer1 VALU + layer2 MFMA), 4 rounds x 128 px, pixel-major out ----
    const int w = tid >> 6, l = tid & 63;
    const int n0 = l & 15, kq = l >> 4;
    const v8h* Bp = (const v8h*)(wsB + ((size_t)stage * 64 + l) * 16);
    const v8h B0 = Bp[0], B1 = Bp[1];
    const float bias0 = b2[n0], bias1 = b2[n0 + 16];
    const int half = w & 1;
    const int pxr = ((w >> 1) << 6) + l;

    #pragma unroll 1
    for (int round = 0; round < 4; round++) {
        int px = round * 128 + pxr;
        union { _Float16 h[8]; float4 f4; } pk0, pk1;
        if (px < TPIX) {
            int r = px / TP, c = px - r * TP;
            int gh = refl(h0 - RAD + r), gw = refl(w0 - RAD + c);
            const float* gp = guid + (size_t)(b * 3) * HW + (size_t)gh * GWW + gw;
            float g0 = gp[0], g1 = gp[HW], g2 = gp[2 * HW];
            #pragma unroll
            for (int kk = 0; kk < 8; kk++) {
                int ch = half * 16 + kk;
                float v = w1[ch * 3] * g0 + w1[ch * 3 + 1] * g1 + w1[ch * 3 + 2] * g2 + b1[ch];
                pk0.h[kk] = (_Float16)gelu_fast(v);
            }
            #pragma unroll
            for (int kk = 0; kk < 8; kk++) {
                int ch = half * 16 + 8 + kk;
                float v = w1[ch * 3] * g0 + w1[ch * 3 + 1] * g1 + w1[ch * 3 + 2] * g2 + b1[ch];
                pk1.h[kk] = (_Float16)gelu_fast(v);
            }
        } else {
            pk0.f4 = make_float4(0.f, 0.f, 0.f, 0.f);
            pk1.f4 = make_float4(0.f, 0.f, 0.f, 0.f);
        }
        *(float4*)(scr + (half * 2) * SHP + pxr * 16)     = pk0.f4;
        *(float4*)(scr + (half * 2 + 1) * SHP + pxr * 16) = pk1.f4;
        __syncthreads();
        #pragma unroll
        for (int tt = 0; tt < 2; tt++) {
            int mb = w * 32 + tt * 16;
            v8h A = *(const v8h*)(scr + kq * SHP + (mb + n0) * 16);
            v4f D0 = {0.f, 0.f, 0.f, 0.f}, D1 = {0.f, 0.f, 0.f, 0.f};
            D0 = __builtin_amdgcn_mfma_f32_16x16x32_f16(A, B0, D0, 0, 0, 0);
            D1 = __builtin_amdgcn_mfma_f32_16x16x32_f16(A, B1, D1, 0, 0, 0);
            #pragma unroll
            for (int r = 0; r < 4; r++) {
                int g = round * 128 + mb + 4 * kq + r;   // C/D row = pixel
                if (g < TPIX) {
                    *(_Float16*)(qpm + g * 64 + n0 * 2)      = (_Float16)(D0[r] + bias0);
                    *(_Float16*)(qpm + g * 64 + 32 + n0 * 2) = (_Float16)(D1[r] + bias1);
                }
            }
        }
        __syncthreads();
    }

    // ---- phase 1: scores via MFMA (A = halo-row px, B = center px -> D col = center px) ----
    // center B-frags for this wave's 4 pixel rows (r = 4w+rr), cached in regs
    v8h Bc[4];
    #pragma unroll
    for (int rr = 0; rr < 4; rr++) {
        int r = 4 * w + rr;
        Bc[rr] = *(const v8h*)(qpm + ((r + RAD) * TP + RAD + n0) * 64 + kq * 16);
    }
    char* myscr = scr + w * SCR_W;
    char* rowscr = scr + (ty >> 2) * SCR_W + (ty & 3) * SCR_R + tx * SCR_N;

    float s[NPTS];
    #pragma unroll
    for (int di = 0; di < DIAM; di++) {
        #pragma unroll
        for (int rr = 0; rr < 4; rr++) {
            int hrow = 4 * w + rr + di;            // halo row, 0..21
            const char* abase = qpm + (hrow * TP + n0) * 64 + kq * 16;
            v8h A0 = *(const v8h*)abase;
            v8h A1 = *(const v8h*)(abase + 16 * 64);
            v4f D0 = {0.f, 0.f, 0.f, 0.f}, D1 = {0.f, 0.f, 0.f, 0.f};
            D0 = __builtin_amdgcn_mfma_f32_16x16x32_f16(A0, Bc[rr], D0, 0, 0, 0);
            D1 = __builtin_amdgcn_mfma_f32_16x16x32_f16(A1, Bc[rr], D1, 0, 0, 0);
            // lane holds center px n0, halo cols m = 4kq+r (D0) / 16+4kq+r (D1)
            union { _Float16 h[4]; uint2 u; } p0, p1;
            #pragma unroll
            for (int r2 = 0; r2 < 4; r2++) { p0.h[r2] = (_Float16)D0[r2]; p1.h[r2] = (_Float16)D1[r2]; }
            char* wdst = myscr + rr * SCR_R + n0 * SCR_N;
            *(uint2*)(wdst + kq * 8)      = p0.u;
            *(uint2*)(wdst + 32 + kq * 8) = p1.u;
        }
        __syncthreads();   // RAW guard (wave-private scratch; insurance vs reordering)
        #pragma unroll
        for (int dj = 0; dj < DIAM; dj++)
            s[di * 7 + dj] = (float)*(const _Float16*)(rowscr + 2 * (tx + dj));
        __builtin_amdgcn_wave_barrier();  // WAR guard: next di's writes stay below reads
        __syncthreads();
    }

    // ---- softmax * spatial, renormalize ----
    float t = __expf(temps[stage]);
    t = fminf(fmaxf(t, 1e-4f), 1e4f);
    float sig = sigmas[stage];
    float inv2s2 = 1.f / (2.f * sig * sig);
    float m = -1e30f;
    #pragma unroll
    for (int p2 = 0; p2 < NPTS; p2++) { s[p2] *= t; m = fmaxf(m, s[p2]); }
    float den = 0.f;
    #pragma unroll
    for (int p2 = 0; p2 < NPTS; p2++) { s[p2] = __expf(s[p2] - m); den += s[p2]; }
    float rden = 1.f / den;
    float ksum = 0.f;
    #pragma unroll
    for (int p2 = 0; p2 < NPTS; p2++) {
        int di = p2 / 7, dj = p2 % 7;
        float dy = (float)(di - 3) * (1.f / 3.f);
        float dx = (float)(dj - 3) * (1.f / 3.f);
        float spat = __expf(-(dy * dy + dx * dx) * inv2s2);
        s[p2] = s[p2] * rden * spat;
        ksum += s[p2];
    }
    float rk = 1.f / fmaxf(ksum, 1e-7f);

    // ---- adaptive conv from sh ----
    float o0 = 0.f, o1 = 0.f, o2 = 0.f;
    int p = 0;
    #pragma unroll
    for (int di = 0; di < DIAM; di++) {
        int rb = (ty + di) * TP + tx;
        #pragma unroll
        for (int dj = 0; dj < DIAM; dj++, p++) {
            float4 hv = sh[rb + dj];
            float kp = s[p] * rk;
            o0 += kp * hv.x;
            o1 += kp * hv.y;
            o2 += kp * hv.z;
        }
    }
    size_t obase = (size_t)b * 3 * HW + (size_t)(h0 + ty) * GWW + (w0 + tx);
    outF[obase]          = o0;
    outF[obase + HW]     = o1;
    outF[obase + 2 * HW] = o2;
}

extern "C" void kernel_launch(void* const* d_in, const int* in_sizes, int n_in,
                              void* d_out, int out_size, void* d_ws, size_t ws_size,
                              hipStream_t stream) {
    const float* x      = (const float*)d_in[0];
    const float* guid   = (const float*)d_in[1];
    const float* lw     = (const float*)d_in[2];
    const float* lb     = (const float*)d_in[3];
    const float* w1s    = (const float*)d_in[4];
    const float* b1s    = (const float*)d_in[5];
    const float* w2s    = (const float*)d_in[6];
    const float* b2s    = (const float*)d_in[7];
    const float* temps  = (const float*)d_in[8];
    const float* sigmas = (const float*)d_in[9];

    char* ws = (char*)d_ws;
    const size_t F_BYTES = (size_t)BATCH * 3 * HW * sizeof(float);    //  4,816,896
    float* hrA  = (float*)ws;
    float* hrB  = (float*)(ws + F_BYTES);
    float* f0   = (float*)(ws + 2 * F_BYTES);                         // 31,104 B
    __half* wsB = (__half*)(ws + 2 * F_BYTES + 31104);                //  8,192 B

    linear_prep_kernel<<<1945, 256, 0, stream>>>(x, lw, lb, f0, w2s, wsB);
    bicubic_kernel<<<(BATCH * 3 * HW + 255) / 256, 256, 0, stream>>>(f0, hrA);

    dim3 jgrid(14, 14, BATCH), jblock(16, 16);
    const float* hins[4]  = { hrA, hrB, hrA, hrB };
    float*       fouts[4] = { hrB, hrA, hrB, (float*)d_out };
    for (int s = 0; s < 4; s++) {
        jbu_kernel<<<jgrid, jblock, 0, stream>>>(
            guid, w1s + s * 96, b1s + s * 32, wsB, b2s + s * 32,
            hins[s], fouts[s], temps, sigmas, s);
    }
}

// Round 12
// 346.588 us; speedup vs baseline: 1.0458x; 1.0458x over previous
//
#include <hip/hip_runtime.h>
#include <hip/hip_fp16.h>
#include <math.h>

#define GHH 224
#define GWW 224
#define HW (GHH*GWW)     // 50176
#define BATCH 8
#define RAD 3
#define DIAM 7
#define NPTS 49
#define QC 32
#define TILE 16
#define TP (TILE + 2*RAD)   // 22
#define TPIX (TP*TP)        // 484
#define SHP 2112            // q-compute round scratch plane stride (bytes)
// smem carve (bytes): qpm 500px*64 = 32000 | sh 484*16 = 7744 | scr 4*4640 = 18560
#define QPM_B 32000
#define SH_B  7744
#define SCR_W 4640          // per-wave scratch stride
#define SCR_R 1160          // per-row stride inside wave scratch
#define SCR_N 72            // per-center-px stride

typedef _Float16 v8h __attribute__((ext_vector_type(8)));
typedef float v4f __attribute__((ext_vector_type(4)));

__device__ __forceinline__ int refl(int i) {
    if (i < 0) i = -i;
    if (i >= GHH) i = 2 * GHH - 2 - i;
    return i;
}

__device__ __forceinline__ float gelu_fast(float v) {
    float u = 0.7978845608f * v * (1.f + 0.044715f * v * v);
    float e = __expf(2.f * u);
    float th = 1.f - 2.f / (e + 1.f);
    return 0.5f * v * (1.f + th);
}

// ---------------- linear (+ fused w2 B-frag prep in extra block) ----------------
__global__ void linear_prep_kernel(const float* __restrict__ x,
                                   const float* __restrict__ W,
                                   const float* __restrict__ bias,
                                   float* __restrict__ f0,
                                   const float* __restrict__ w2s,
                                   __half* __restrict__ wsB) {
    if (blockIdx.x == 1944) {   // prep: pack w2 (4 stages) into f16 MFMA B-fragments
        int tid = threadIdx.x;  // 256 = 4 stages x 64 lanes
        int s = tid >> 6, l = tid & 63;
        int n0 = l & 15, kq = l >> 4;
        const float* w2 = w2s + s * 1024;
        __half* dst = wsB + (size_t)tid * 16;
        #pragma unroll
        for (int j = 0; j < 8; j++) {
            dst[j]     = __float2half(w2[n0 * QC + kq * 8 + j]);
            dst[8 + j] = __float2half(w2[(n0 + 16) * QC + kq * 8 + j]);
        }
        return;
    }
    int gwave = (blockIdx.x * blockDim.x + threadIdx.x) >> 6;
    int lane = threadIdx.x & 63;
    if (gwave >= BATCH * 972) return;
    int b = gwave / 972, j = gwave % 972;
    const float* xr = x + b * 1000;
    const float* wr = W + j * 1000;
    float s = 0.f;
    for (int k = lane; k < 1000; k += 64)
        s += xr[k] * wr[k];
    #pragma unroll
    for (int off = 32; off; off >>= 1) s += __shfl_down(s, off, 64);
    if (lane == 0) f0[gwave] = s + bias[j];
}

// ---------------- bicubic 18 -> 224 ----------------
__device__ __forceinline__ float cubicw(float d) {
    d = fabsf(d);
    if (d <= 1.f) return ((1.25f * d - 2.25f) * d) * d + 1.f;
    if (d < 2.f)  return ((-0.75f * d + 3.75f) * d - 6.f) * d + 3.f;
    return 0.f;
}

__global__ void bicubic_kernel(const float* __restrict__ f0, float* __restrict__ hr) {
    int idx = blockIdx.x * blockDim.x + threadIdx.x;
    if (idx >= BATCH * 3 * HW) return;
    int w = idx % GWW;
    int h = (idx / GWW) % GHH;
    int bc = idx / HW;
    const float* src = f0 + bc * 18 * 18;
    float xx = (w + 0.5f) * (18.f / 224.f) - 0.5f;
    float yy = (h + 0.5f) * (18.f / 224.f) - 0.5f;
    float fx0 = floorf(xx), fy0 = floorf(yy);
    int x0 = (int)fx0, y0 = (int)fy0;
    float tx = xx - fx0, ty = yy - fy0;
    float wx[4], wy[4];
    int ix[4], iy[4];
    #pragma unroll
    for (int k = 0; k < 4; k++) {
        wx[k] = cubicw(tx - (float)(k - 1));
        wy[k] = cubicw(ty - (float)(k - 1));
        int a = x0 + (k - 1); ix[k] = min(max(a, 0), 17);
        a = y0 + (k - 1);     iy[k] = min(max(a, 0), 17);
    }
    float acc = 0.f;
    #pragma unroll
    for (int ky = 0; ky < 4; ky++) {
        float rowv = 0.f;
        #pragma unroll
        for (int kx = 0; kx < 4; kx++) rowv += wx[kx] * src[iy[ky] * 18 + ix[kx]];
        acc += wy[ky] * rowv;
    }
    hr[idx] = acc;
}

// ---------------- fully fused JBU: q-compute (MFMA) + MFMA scores + softmax + conv ----------------
__global__ __launch_bounds__(256, 2) void jbu_kernel(
    const float* __restrict__ guid,
    const float* __restrict__ w1, const float* __restrict__ b1,
    const __half* __restrict__ wsB, const float* __restrict__ b2,
    const float* __restrict__ hr,
    float* __restrict__ outF,
    const float* __restrict__ temps,
    const float* __restrict__ sigmas,
    int stage)
{
    __shared__ __align__(16) char smem[QPM_B + SH_B + 4 * SCR_W];  // 58304 B
    char*   qpm = smem;                         // q tile, pixel-major f16 [500 px][64 B]
    float4* sh  = (float4*)(smem + QPM_B);      // hr tile (3ch + pad)
    char*   scr = smem + QPM_B + SH_B;          // wave-private score scratch / q-round scratch

    const int tx = threadIdx.x, ty = threadIdx.y;
    const int tid = ty * TILE + tx;
    const int b = blockIdx.z;
    const int h0 = blockIdx.y * TILE, w0 = blockIdx.x * TILE;

    // ---- stage hr tile ----
    const bool interior = (h0 >= RAD) && (h0 + TILE + RAD <= GHH) &&
                          (w0 >= RAD) && (w0 + TILE + RAD <= GWW);
    if (interior) {
        const float* hb = hr + (size_t)b * 3 * HW + (size_t)(h0 - RAD) * GWW + (w0 - RAD);
        for (int i = tid; i < TPIX; i += 256) {
            int r = i / TP, cx = i % TP;
            size_t base = (size_t)r * GWW + cx;
            sh[i] = make_float4(hb[base], hb[base + HW], hb[base + 2 * HW], 0.f);
        }
    } else {
        for (int i = tid; i < TPIX; i += 256) {
            int r = i / TP, cx = i % TP;
            int gh = refl(h0 - RAD + r);
            int gw = refl(w0 - RAD + cx);
            size_t base = (size_t)b * 3 * HW + (size_t)gh * GWW + gw;
            sh[i] = make_float4(hr[base], hr[base + HW], hr[base + 2 * HW], 0.f);
        }
    }

    // ---- phase 0: q tile (layer1 VALU + layer2 MFMA), 4 rounds x 128 px, pixel-major out ----
    const int w = tid >> 6, l = tid & 63;
    const int n0 = l & 15, kq = l >> 4;
    const v8h* Bp = (const v8h*)(wsB + ((size_t)stage * 64 + l) * 16);
    const v8h B0 = Bp[0], B1 = Bp[1];
    const float bias0 = b2[n0], bias1 = b2[n0 + 16];
    const int half = w & 1;
    const int pxr = ((w >> 1) << 6) + l;

    #pragma unroll 1
    for (int round = 0; round < 4; round++) {
        int px = round * 128 + pxr;
        union { _Float16 h[8]; float4 f4; } pk0, pk1;
        if (px < TPIX) {
            int r = px / TP, c = px - r * TP;
            int gh = refl(h0 - RAD + r), gw = refl(w0 - RAD + c);
            const float* gp = guid + (size_t)(b * 3) * HW + (size_t)gh * GWW + gw;
            float g0 = gp[0], g1 = gp[HW], g2 = gp[2 * HW];
            #pragma unroll
            for (int kk = 0; kk < 8; kk++) {
                int ch = half * 16 + kk;
                float v = w1[ch * 3] * g0 + w1[ch * 3 + 1] * g1 + w1[ch * 3 + 2] * g2 + b1[ch];
                pk0.h[kk] = (_Float16)gelu_fast(v);
            }
            #pragma unroll
            for (int kk = 0; kk < 8; kk++) {
                int ch = half * 16 + 8 + kk;
                float v = w1[ch * 3] * g0 + w1[ch * 3 + 1] * g1 + w1[ch * 3 + 2] * g2 + b1[ch];
                pk1.h[kk] = (_Float16)gelu_fast(v);
            }
        } else {
            pk0.f4 = make_float4(0.f, 0.f, 0.f, 0.f);
            pk1.f4 = make_float4(0.f, 0.f, 0.f, 0.f);
        }
        *(float4*)(scr + (half * 2) * SHP + pxr * 16)     = pk0.f4;
        *(float4*)(scr + (half * 2 + 1) * SHP + pxr * 16) = pk1.f4;
        __syncthreads();
        #pragma unroll
        for (int tt = 0; tt < 2; tt++) {
            int mb = w * 32 + tt * 16;
            v8h A = *(const v8h*)(scr + kq * SHP + (mb + n0) * 16);
            v4f D0 = {0.f, 0.f, 0.f, 0.f}, D1 = {0.f, 0.f, 0.f, 0.f};
            D0 = __builtin_amdgcn_mfma_f32_16x16x32_f16(A, B0, D0, 0, 0, 0);
            D1 = __builtin_amdgcn_mfma_f32_16x16x32_f16(A, B1, D1, 0, 0, 0);
            #pragma unroll
            for (int r = 0; r < 4; r++) {
                int g = round * 128 + mb + 4 * kq + r;   // C/D row = pixel
                if (g < TPIX) {
                    *(_Float16*)(qpm + g * 64 + n0 * 2)      = (_Float16)(D0[r] + bias0);
                    *(_Float16*)(qpm + g * 64 + 32 + n0 * 2) = (_Float16)(D1[r] + bias1);
                }
            }
        }
        __syncthreads();
    }

    // ---- phase 1: scores via MFMA (A = halo-row px, B = center px -> D col = center px) ----
    // scratch is WAVE-PRIVATE: no __syncthreads needed, only same-wave DS ordering
    v8h Bc[4];
    #pragma unroll
    for (int rr = 0; rr < 4; rr++) {
        int r = 4 * w + rr;
        Bc[rr] = *(const v8h*)(qpm + ((r + RAD) * TP + RAD + n0) * 64 + kq * 16);
    }
    char* myscr = scr + w * SCR_W;
    char* rowscr = scr + (ty >> 2) * SCR_W + (ty & 3) * SCR_R + tx * SCR_N;

    float s[NPTS];
    #pragma unroll
    for (int di = 0; di < DIAM; di++) {
        #pragma unroll
        for (int rr = 0; rr < 4; rr++) {
            int hrow = 4 * w + rr + di;            // halo row, 0..21
            const char* abase = qpm + (hrow * TP + n0) * 64 + kq * 16;
            v8h A0 = *(const v8h*)abase;
            v8h A1 = *(const v8h*)(abase + 16 * 64);
            v4f D0 = {0.f, 0.f, 0.f, 0.f}, D1 = {0.f, 0.f, 0.f, 0.f};
            D0 = __builtin_amdgcn_mfma_f32_16x16x32_f16(A0, Bc[rr], D0, 0, 0, 0);
            D1 = __builtin_amdgcn_mfma_f32_16x16x32_f16(A1, Bc[rr], D1, 0, 0, 0);
            // lane holds center px n0; halo cols m = 4kq+r2 (D0) / 16+4kq+r2 (D1)
            union { _Float16 h[4]; uint2 u; } p0, p1;
            #pragma unroll
            for (int r2 = 0; r2 < 4; r2++) { p0.h[r2] = (_Float16)D0[r2]; p1.h[r2] = (_Float16)D1[r2]; }
            char* wdst = myscr + rr * SCR_R + n0 * SCR_N;
            *(uint2*)(wdst + kq * 8)      = p0.u;
            *(uint2*)(wdst + 32 + kq * 8) = p1.u;
        }
        // same-wave RAW: drain DS queue, and fence the compiler
        asm volatile("s_waitcnt lgkmcnt(0)" ::: "memory");
        #pragma unroll
        for (int dj = 0; dj < DIAM; dj++)
            s[di * 7 + dj] = (float)*(const _Float16*)(rowscr + 2 * (tx + dj));
        asm volatile("" ::: "memory");   // keep next di's writes below these reads
    }

    // ---- softmax * spatial, renormalize ----
    float t = __expf(temps[stage]);
    t = fminf(fmaxf(t, 1e-4f), 1e4f);
    float sig = sigmas[stage];
    float inv2s2 = 1.f / (2.f * sig * sig);
    float m = -1e30f;
    #pragma unroll
    for (int p2 = 0; p2 < NPTS; p2++) { s[p2] *= t; m = fmaxf(m, s[p2]); }
    float den = 0.f;
    #pragma unroll
    for (int p2 = 0; p2 < NPTS; p2++) { s[p2] = __expf(s[p2] - m); den += s[p2]; }
    float rden = 1.f / den;
    float ksum = 0.f;
    #pragma unroll
    for (int p2 = 0; p2 < NPTS; p2++) {
        int di = p2 / 7, dj = p2 % 7;
        float dy = (float)(di - 3) * (1.f / 3.f);
        float dx = (float)(dj - 3) * (1.f / 3.f);
        float spat = __expf(-(dy * dy + dx * dx) * inv2s2);
        s[p2] = s[p2] * rden * spat;
        ksum += s[p2];
    }
    float rk = 1.f / fmaxf(ksum, 1e-7f);

    // ---- adaptive conv from sh ----
    float o0 = 0.f, o1 = 0.f, o2 = 0.f;
    int p = 0;
    #pragma unroll
    for (int di = 0; di < DIAM; di++) {
        int rb = (ty + di) * TP + tx;
        #pragma unroll
        for (int dj = 0; dj < DIAM; dj++, p++) {
            float4 hv = sh[rb + dj];
            float kp = s[p] * rk;
            o0 += kp * hv.x;
            o1 += kp * hv.y;
            o2 += kp * hv.z;
        }
    }
    size_t obase = (size_t)b * 3 * HW + (size_t)(h0 + ty) * GWW + (w0 + tx);
    outF[obase]          = o0;
    outF[obase + HW]     = o1;
    outF[obase + 2 * HW] = o2;
}

extern "C" void kernel_launch(void* const* d_in, const int* in_sizes, int n_in,
                              void* d_out, int out_size, void* d_ws, size_t ws_size,
                              hipStream_t stream) {
    const float* x      = (const float*)d_in[0];
    const float* guid   = (const float*)d_in[1];
    const float* lw     = (const float*)d_in[2];
    const float* lb     = (const float*)d_in[3];
    const float* w1s    = (const float*)d_in[4];
    const float* b1s    = (const float*)d_in[5];
    const float* w2s    = (const float*)d_in[6];
    const float* b2s    = (const float*)d_in[7];
    const float* temps  = (const float*)d_in[8];
    const float* sigmas = (const float*)d_in[9];

    char* ws = (char*)d_ws;
    const size_t F_BYTES = (size_t)BATCH * 3 * HW * sizeof(float);    //  4,816,896
    float* hrA  = (float*)ws;
    float* hrB  = (float*)(ws + F_BYTES);
    float* f0   = (float*)(ws + 2 * F_BYTES);                         // 31,104 B
    __half* wsB = (__half*)(ws + 2 * F_BYTES + 31104);                //  8,192 B

    linear_prep_kernel<<<1945, 256, 0, stream>>>(x, lw, lb, f0, w2s, wsB);
    bicubic_kernel<<<(BATCH * 3 * HW + 255) / 256, 256, 0, stream>>>(f0, hrA);

    dim3 jgrid(14, 14, BATCH), jblock(16, 16);
    const float* hins[4]  = { hrA, hrB, hrA, hrB };
    float*       fouts[4] = { hrB, hrA, hrB, (float*)d_out };
    for (int s = 0; s < 4; s++) {
        jbu_kernel<<<jgrid, jblock, 0, stream>>>(
            guid, w1s + s * 96, b1s + s * 32, wsB, b2s + s * 32,
            hins[s], fouts[s], temps, sigmas, s);
    }
}

// Round 13
// 346.202 us; speedup vs baseline: 1.0470x; 1.0011x over previous
//
#include <hip/hip_runtime.h>
#include <hip/hip_fp16.h>
#include <math.h>

#define GHH 224
#define GWW 224
#define HW (GHH*GWW)     // 50176
#define BATCH 8
#define RAD 3
#define DIAM 7
#define NPTS 49
#define QC 32
#define TILE 16
#define TP (TILE + 2*RAD)   // 22
#define TPIX (TP*TP)        // 484
#define CS 485              // chunk-plane stride in float4 (R8/R10-proven)
// smem carve: sq 4*485*16=31040 | sh 484*16=7744 | sA 4 waves*4096=16384  => 55168 B
#define SQ_B 31040
#define SH_B 7744

typedef _Float16 h2 __attribute__((ext_vector_type(2)));
typedef _Float16 v8h __attribute__((ext_vector_type(8)));
typedef float v4f __attribute__((ext_vector_type(4)));

#if defined(__has_builtin)
#if __has_builtin(__builtin_amdgcn_fdot2)
#define HAS_FDOT2 1
#endif
#endif

__device__ __forceinline__ h2 as_h2(float f) { union { float f; h2 h; } u; u.f = f; return u.h; }

__device__ __forceinline__ float dot2acc(float a, float b, float acc) {
#ifdef HAS_FDOT2
    return __builtin_amdgcn_fdot2(as_h2(a), as_h2(b), acc, false);
#else
    union { float f; __half2 h; } ua, ub; ua.f = a; ub.f = b;
    float2 fa = __half22float2(ua.h), fb = __half22float2(ub.h);
    return acc + fa.x * fb.x + fa.y * fb.y;
#endif
}

__device__ __forceinline__ float dot16(const float4& a, const float4& b, float acc) {
    acc = dot2acc(a.x, b.x, acc);
    acc = dot2acc(a.y, b.y, acc);
    acc = dot2acc(a.z, b.z, acc);
    acc = dot2acc(a.w, b.w, acc);
    return acc;
}

__device__ __forceinline__ int refl(int i) {
    if (i < 0) i = -i;
    if (i >= GHH) i = 2 * GHH - 2 - i;
    return i;
}

__device__ __forceinline__ float gelu_fast(float v) {
    float u = 0.7978845608f * v * (1.f + 0.044715f * v * v);
    float e = __expf(2.f * u);
    float th = 1.f - 2.f / (e + 1.f);
    return 0.5f * v * (1.f + th);
}

// ---------------- linear + w2 B-frag prep + guid4 pack (independent block ranges) ----------------
__global__ void linear_prep_kernel(const float* __restrict__ x,
                                   const float* __restrict__ W,
                                   const float* __restrict__ bias,
                                   float* __restrict__ f0,
                                   const float* __restrict__ w2s,
                                   __half* __restrict__ wsB,
                                   const float* __restrict__ guid,
                                   float4* __restrict__ guid4) {
    int blk = blockIdx.x;
    if (blk >= 1945) {   // guid4 pack: 1568 blocks
        int i = (blk - 1945) * 256 + threadIdx.x;
        int b = i / HW, pix = i % HW;
        guid4[i] = make_float4(guid[(b * 3) * HW + pix],
                               guid[(b * 3 + 1) * HW + pix],
                               guid[(b * 3 + 2) * HW + pix], 0.f);
        return;
    }
    if (blk == 1944) {   // pack w2 (4 stages) into f16 MFMA B-fragments
        int tid = threadIdx.x;  // 256 = 4 stages x 64 lanes
        int s = tid >> 6, l = tid & 63;
        int n0 = l & 15, kq = l >> 4;
        const float* w2 = w2s + s * 1024;
        __half* dst = wsB + (size_t)tid * 16;
        #pragma unroll
        for (int j = 0; j < 8; j++) {
            dst[j]     = __float2half(w2[n0 * QC + kq * 8 + j]);
            dst[8 + j] = __float2half(w2[(n0 + 16) * QC + kq * 8 + j]);
        }
        return;
    }
    int gwave = (blk * blockDim.x + threadIdx.x) >> 6;
    int lane = threadIdx.x & 63;
    if (gwave >= BATCH * 972) return;
    int b = gwave / 972, j = gwave % 972;
    const float* xr = x + b * 1000;
    const float* wr = W + j * 1000;
    float s = 0.f;
    for (int k = lane; k < 1000; k += 64)
        s += xr[k] * wr[k];
    #pragma unroll
    for (int off = 32; off; off >>= 1) s += __shfl_down(s, off, 64);
    if (lane == 0) f0[gwave] = s + bias[j];
}

// ---------------- bicubic 18 -> 224, float4-interleaved output ----------------
__device__ __forceinline__ float cubicw(float d) {
    d = fabsf(d);
    if (d <= 1.f) return ((1.25f * d - 2.25f) * d) * d + 1.f;
    if (d < 2.f)  return ((-0.75f * d + 3.75f) * d - 6.f) * d + 3.f;
    return 0.f;
}

__global__ void bicubic_kernel(const float* __restrict__ f0, float4* __restrict__ hr4) {
    int idx = blockIdx.x * blockDim.x + threadIdx.x;
    if (idx >= BATCH * HW) return;
    int pix = idx % HW;
    int b = idx / HW;
    int w = pix % GWW, h = pix / GWW;
    float xx = (w + 0.5f) * (18.f / 224.f) - 0.5f;
    float yy = (h + 0.5f) * (18.f / 224.f) - 0.5f;
    float fx0 = floorf(xx), fy0 = floorf(yy);
    int x0 = (int)fx0, y0 = (int)fy0;
    float tx = xx - fx0, ty = yy - fy0;
    float wx[4], wy[4];
    int ix[4], iy[4];
    #pragma unroll
    for (int k = 0; k < 4; k++) {
        wx[k] = cubicw(tx - (float)(k - 1));
        wy[k] = cubicw(ty - (float)(k - 1));
        int a = x0 + (k - 1); ix[k] = min(max(a, 0), 17);
        a = y0 + (k - 1);     iy[k] = min(max(a, 0), 17);
    }
    float acc[3];
    #pragma unroll
    for (int c = 0; c < 3; c++) {
        const float* src = f0 + (b * 3 + c) * 324;
        float a = 0.f;
        #pragma unroll
        for (int ky = 0; ky < 4; ky++) {
            float rowv = 0.f;
            #pragma unroll
            for (int kx = 0; kx < 4; kx++) rowv += wx[kx] * src[iy[ky] * 18 + ix[kx]];
            a += wy[ky] * rowv;
        }
        acc[c] = a;
    }
    hr4[idx] = make_float4(acc[0], acc[1], acc[2], 0.f);
}

// ---------------- fully fused JBU: wave-private q-compute (MFMA) + fdot2 scores + conv ----------------
__global__ __launch_bounds__(256, 2) void jbu_kernel(
    const float4* __restrict__ guid4,
    const float* __restrict__ w1, const float* __restrict__ b1,
    const __half* __restrict__ wsB, const float* __restrict__ b2,
    const float4* __restrict__ hr4,
    float4* __restrict__ out4,
    float* __restrict__ outP,
    const float* __restrict__ temps,
    const float* __restrict__ sigmas,
    int stage)
{
    __shared__ __align__(16) char smem[SQ_B + SH_B + 16384];  // 55168 B
    float4* sq = (float4*)smem;                 // q tile f16 chunk-planar [4][CS]
    float4* sh = (float4*)(smem + SQ_B);        // hr tile (3ch + pad)
    char*   sA = smem + SQ_B + SH_B;            // wave-private h1 scratch, 4 KB/wave

    const int tx = threadIdx.x, ty = threadIdx.y;
    const int tid = ty * TILE + tx;
    const int b = blockIdx.z;
    const int h0 = blockIdx.y * TILE, w0 = blockIdx.x * TILE;

    // ---- stage hr tile (single float4 load per halo px) ----
    const bool interior = (h0 >= RAD) && (h0 + TILE + RAD <= GHH) &&
                          (w0 >= RAD) && (w0 + TILE + RAD <= GWW);
    if (interior) {
        const float4* hb = hr4 + (size_t)b * HW + (size_t)(h0 - RAD) * GWW + (w0 - RAD);
        for (int i = tid; i < TPIX; i += 256) {
            int r = i / TP, cx = i % TP;
            sh[i] = hb[(size_t)r * GWW + cx];
        }
    } else {
        for (int i = tid; i < TPIX; i += 256) {
            int r = i / TP, cx = i % TP;
            int gh = refl(h0 - RAD + r);
            int gw = refl(w0 - RAD + cx);
            sh[i] = hr4[(size_t)b * HW + (size_t)gh * GWW + gw];
        }
    }

    // ---- phase 0: q tile, wave-private (no block barriers inside) ----
    const int w = tid >> 6, l = tid & 63;
    const int n0 = l & 15, kq = l >> 4;
    const v8h* Bp = (const v8h*)(wsB + ((size_t)stage * 64 + l) * 16);
    const v8h B0 = Bp[0], B1 = Bp[1];
    const float bias0 = b2[n0], bias1 = b2[n0 + 16];
    char* wsc = sA + w * 4096;

    #pragma unroll 1
    for (int round = 0; round < 2; round++) {
        int px = round * 256 + w * 64 + l;
        float4 pk[4];
        if (px < TPIX) {
            int r = px / TP, c = px - r * TP;
            int gh = refl(h0 - RAD + r), gw = refl(w0 - RAD + c);
            float4 g = guid4[(size_t)b * HW + (size_t)gh * GWW + gw];
            #pragma unroll
            for (int cc = 0; cc < 4; cc++) {
                union { _Float16 h[8]; float4 f4; } u;
                #pragma unroll
                for (int j = 0; j < 8; j++) {
                    int ch = cc * 8 + j;
                    float v = w1[ch * 3] * g.x + w1[ch * 3 + 1] * g.y + w1[ch * 3 + 2] * g.z + b1[ch];
                    u.h[j] = (_Float16)gelu_fast(v);
                }
                pk[cc] = u.f4;
            }
        } else {
            pk[0] = pk[1] = pk[2] = pk[3] = make_float4(0.f, 0.f, 0.f, 0.f);
        }
        *(float4*)(wsc + l * 64)      = pk[0];
        *(float4*)(wsc + l * 64 + 16) = pk[1];
        *(float4*)(wsc + l * 64 + 32) = pk[2];
        *(float4*)(wsc + l * 64 + 48) = pk[3];
        asm volatile("s_waitcnt lgkmcnt(0)" ::: "memory");  // wave-private RAW
        #pragma unroll
        for (int tt = 0; tt < 4; tt++) {
            v8h A = *(const v8h*)(wsc + (tt * 16 + n0) * 64 + kq * 16);
            v4f D0 = {0.f, 0.f, 0.f, 0.f}, D1 = {0.f, 0.f, 0.f, 0.f};
            D0 = __builtin_amdgcn_mfma_f32_16x16x32_f16(A, B0, D0, 0, 0, 0);
            D1 = __builtin_amdgcn_mfma_f32_16x16x32_f16(A, B1, D1, 0, 0, 0);
            #pragma unroll
            for (int r = 0; r < 4; r++) {
                int g = round * 256 + w * 64 + tt * 16 + 4 * kq + r;   // C/D row = pixel
                if (g < TPIX) {
                    *(_Float16*)(smem + ((n0 >> 3) * CS + g) * 16 + (n0 & 7) * 2)
                        = (_Float16)(D0[r] + bias0);
                    *(_Float16*)(smem + (((n0 >> 3) + 2) * CS + g) * 16 + (n0 & 7) * 2)
                        = (_Float16)(D1[r] + bias1);
                }
            }
        }
        asm volatile("" ::: "memory");   // keep round r+1 writes below round r reads
    }
    __syncthreads();   // single barrier: qpm + sh ready for all waves

    // ---- phase 1: scores (R8/R10-proven fdot2 structure, 1 px/thread) ----
    int ci = (ty + RAD) * TP + tx + RAD;
    float4 c0 = sq[ci], c1 = sq[CS + ci], c2 = sq[2 * CS + ci], c3 = sq[3 * CS + ci];

    float s[NPTS];
    int p = 0;
    #pragma unroll
    for (int di = 0; di < DIAM; di++) {
        int rb = (ty + di) * TP + tx;
        #pragma unroll
        for (int dj = 0; dj < DIAM; dj++, p++) {
            int ni = rb + dj;
            float acc = dot16(c0, sq[ni], 0.f);
            acc = dot16(c1, sq[CS + ni], acc);
            acc = dot16(c2, sq[2 * CS + ni], acc);
            acc = dot16(c3, sq[3 * CS + ni], acc);
            s[p] = acc;
        }
    }

    // ---- softmax * spatial, renormalize ----
    float t = __expf(temps[stage]);
    t = fminf(fmaxf(t, 1e-4f), 1e4f);
    float sig = sigmas[stage];
    float inv2s2 = 1.f / (2.f * sig * sig);
    float m = -1e30f;
    #pragma unroll
    for (int p2 = 0; p2 < NPTS; p2++) { s[p2] *= t; m = fmaxf(m, s[p2]); }
    float den = 0.f;
    #pragma unroll
    for (int p2 = 0; p2 < NPTS; p2++) { s[p2] = __expf(s[p2] - m); den += s[p2]; }
    float rden = 1.f / den;
    float ksum = 0.f;
    #pragma unroll
    for (int p2 = 0; p2 < NPTS; p2++) {
        int di = p2 / 7, dj = p2 % 7;
        float dy = (float)(di - 3) * (1.f / 3.f);
        float dx = (float)(dj - 3) * (1.f / 3.f);
        float spat = __expf(-(dy * dy + dx * dx) * inv2s2);
        s[p2] = s[p2] * rden * spat;
        ksum += s[p2];
    }
    float rk = 1.f / fmaxf(ksum, 1e-7f);

    // ---- adaptive conv from sh ----
    float o0 = 0.f, o1 = 0.f, o2 = 0.f;
    p = 0;
    #pragma unroll
    for (int di = 0; di < DIAM; di++) {
        int rb = (ty + di) * TP + tx;
        #pragma unroll
        for (int dj = 0; dj < DIAM; dj++, p++) {
            float4 hv = sh[rb + dj];
            float kp = s[p] * rk;
            o0 += kp * hv.x;
            o1 += kp * hv.y;
            o2 += kp * hv.z;
        }
    }
    if (stage < 3) {
        out4[(size_t)b * HW + (size_t)(h0 + ty) * GWW + (w0 + tx)] = make_float4(o0, o1, o2, 0.f);
    } else {
        size_t obase = (size_t)b * 3 * HW + (size_t)(h0 + ty) * GWW + (w0 + tx);
        outP[obase]          = o0;
        outP[obase + HW]     = o1;
        outP[obase + 2 * HW] = o2;
    }
}

extern "C" void kernel_launch(void* const* d_in, const int* in_sizes, int n_in,
                              void* d_out, int out_size, void* d_ws, size_t ws_size,
                              hipStream_t stream) {
    const float* x      = (const float*)d_in[0];
    const float* guid   = (const float*)d_in[1];
    const float* lw     = (const float*)d_in[2];
    const float* lb     = (const float*)d_in[3];
    const float* w1s    = (const float*)d_in[4];
    const float* b1s    = (const float*)d_in[5];
    const float* w2s    = (const float*)d_in[6];
    const float* b2s    = (const float*)d_in[7];
    const float* temps  = (const float*)d_in[8];
    const float* sigmas = (const float*)d_in[9];

    char* ws = (char*)d_ws;
    const size_t P4_BYTES = (size_t)BATCH * HW * sizeof(float4);      // 6,422,528
    float4* guid4 = (float4*)ws;
    float4* hr4A  = (float4*)(ws + P4_BYTES);
    float4* hr4B  = (float4*)(ws + 2 * P4_BYTES);
    float*  f0    = (float*)(ws + 3 * P4_BYTES);                      // 31,104 B
    __half* wsB   = (__half*)(ws + 3 * P4_BYTES + 31104);             //  8,192 B

    linear_prep_kernel<<<1945 + 1568, 256, 0, stream>>>(x, lw, lb, f0, w2s, wsB, guid, guid4);
    bicubic_kernel<<<(BATCH * HW + 255) / 256, 256, 0, stream>>>(f0, hr4A);

    dim3 jgrid(14, 14, BATCH), jblock(16, 16);
    const float4* hins[4]  = { hr4A, hr4B, hr4A, hr4B };
    float4*       fouts[4] = { hr4B, hr4A, hr4B, nullptr };
    for (int s = 0; s < 4; s++) {
        jbu_kernel<<<jgrid, jblock, 0, stream>>>(
            guid4, w1s + s * 96, b1s + s * 32, wsB, b2s + s * 32,
            hins[s], fouts[s], (s == 3) ? (float*)d_out : nullptr,
            temps, sigmas, s);
    }
}

// Round 14
// 294.278 us; speedup vs baseline: 1.2317x; 1.1764x over previous
//
#include <hip/hip_runtime.h>
#include <hip/hip_fp16.h>
#include <math.h>

#define GHH 224
#define GWW 224
#define HW (GHH*GWW)     // 50176
#define BATCH 8
#define RAD 3
#define DIAM 7
#define NPTS 49
#define QC 32
#define TILE 16
#define TP (TILE + 2*RAD)   // 22
#define TPIX (TP*TP)        // 484
#define CS 485              // chunk-plane stride in float4 (proven layout)
// smem: sq 4*485*16 = 31040 | sh 484*16 = 7744  => 38784 B  -> 4 blocks/CU
#define SQ_B 31040

typedef _Float16 h2 __attribute__((ext_vector_type(2)));
typedef _Float16 v8h __attribute__((ext_vector_type(8)));
typedef float v4f __attribute__((ext_vector_type(4)));

#if defined(__has_builtin)
#if __has_builtin(__builtin_amdgcn_fdot2)
#define HAS_FDOT2 1
#endif
#endif

__device__ __forceinline__ h2 as_h2(float f) { union { float f; h2 h; } u; u.f = f; return u.h; }

__device__ __forceinline__ float dot2acc(float a, float b, float acc) {
#ifdef HAS_FDOT2
    return __builtin_amdgcn_fdot2(as_h2(a), as_h2(b), acc, false);
#else
    union { float f; __half2 h; } ua, ub; ua.f = a; ub.f = b;
    float2 fa = __half22float2(ua.h), fb = __half22float2(ub.h);
    return acc + fa.x * fb.x + fa.y * fb.y;
#endif
}

__device__ __forceinline__ float dot16(const float4& a, const float4& b, float acc) {
    acc = dot2acc(a.x, b.x, acc);
    acc = dot2acc(a.y, b.y, acc);
    acc = dot2acc(a.z, b.z, acc);
    acc = dot2acc(a.w, b.w, acc);
    return acc;
}

__device__ __forceinline__ int refl(int i) {
    if (i < 0) i = -i;
    if (i >= GHH) i = 2 * GHH - 2 - i;
    return i;
}

__device__ __forceinline__ float gelu_fast(float v) {
    float u = 0.7978845608f * v * (1.f + 0.044715f * v * v);
    float e = __expf(2.f * u);
    float th = 1.f - 2.f / (e + 1.f);
    return 0.5f * v * (1.f + th);
}

// ---------------- linear + w2 B-frag prep + w1 f16 pack + guid4 pack ----------------
__global__ void linear_prep_kernel(const float* __restrict__ x,
                                   const float* __restrict__ W,
                                   const float* __restrict__ bias,
                                   float* __restrict__ f0,
                                   const float* __restrict__ w2s,
                                   __half* __restrict__ wsB,
                                   const float* __restrict__ w1s,
                                   const float* __restrict__ b1s,
                                   __half* __restrict__ wsW1,
                                   const float* __restrict__ guid,
                                   float4* __restrict__ guid4) {
    int blk = blockIdx.x;
    if (blk >= 1946) {   // guid4 pack: 1568 blocks
        int i = (blk - 1946) * 256 + threadIdx.x;
        int b = i / HW, pix = i % HW;
        guid4[i] = make_float4(guid[(b * 3) * HW + pix],
                               guid[(b * 3 + 1) * HW + pix],
                               guid[(b * 3 + 2) * HW + pix], 0.f);
        return;
    }
    if (blk == 1945) {   // pack w1/b1 (4 stages x 32 ch) into f16 quads (w0,w1,w2,b)
        int tid = threadIdx.x;
        if (tid < 128) {
            int s = tid >> 5, c = tid & 31;
            wsW1[tid * 4 + 0] = __float2half(w1s[s * 96 + c * 3 + 0]);
            wsW1[tid * 4 + 1] = __float2half(w1s[s * 96 + c * 3 + 1]);
            wsW1[tid * 4 + 2] = __float2half(w1s[s * 96 + c * 3 + 2]);
            wsW1[tid * 4 + 3] = __float2half(b1s[s * 32 + c]);
        }
        return;
    }
    if (blk == 1944) {   // pack w2 (4 stages) into f16 MFMA B-fragments
        int tid = threadIdx.x;  // 256 = 4 stages x 64 lanes
        int s = tid >> 6, l = tid & 63;
        int n0 = l & 15, kq = l >> 4;
        const float* w2 = w2s + s * 1024;
        __half* dst = wsB + (size_t)tid * 16;
        #pragma unroll
        for (int j = 0; j < 8; j++) {
            dst[j]     = __float2half(w2[n0 * QC + kq * 8 + j]);
            dst[8 + j] = __float2half(w2[(n0 + 16) * QC + kq * 8 + j]);
        }
        return;
    }
    int gwave = (blk * blockDim.x + threadIdx.x) >> 6;
    int lane = threadIdx.x & 63;
    if (gwave >= BATCH * 972) return;
    int b = gwave / 972, j = gwave % 972;
    const float* xr = x + b * 1000;
    const float* wr = W + j * 1000;
    float s = 0.f;
    for (int k = lane; k < 1000; k += 64)
        s += xr[k] * wr[k];
    #pragma unroll
    for (int off = 32; off; off >>= 1) s += __shfl_down(s, off, 64);
    if (lane == 0) f0[gwave] = s + bias[j];
}

// ---------------- bicubic 18 -> 224, float4-interleaved output ----------------
__device__ __forceinline__ float cubicw(float d) {
    d = fabsf(d);
    if (d <= 1.f) return ((1.25f * d - 2.25f) * d) * d + 1.f;
    if (d < 2.f)  return ((-0.75f * d + 3.75f) * d - 6.f) * d + 3.f;
    return 0.f;
}

__global__ void bicubic_kernel(const float* __restrict__ f0, float4* __restrict__ hr4) {
    int idx = blockIdx.x * blockDim.x + threadIdx.x;
    if (idx >= BATCH * HW) return;
    int pix = idx % HW;
    int b = idx / HW;
    int w = pix % GWW, h = pix / GWW;
    float xx = (w + 0.5f) * (18.f / 224.f) - 0.5f;
    float yy = (h + 0.5f) * (18.f / 224.f) - 0.5f;
    float fx0 = floorf(xx), fy0 = floorf(yy);
    int x0 = (int)fx0, y0 = (int)fy0;
    float tx = xx - fx0, ty = yy - fy0;
    float wx[4], wy[4];
    int ix[4], iy[4];
    #pragma unroll
    for (int k = 0; k < 4; k++) {
        wx[k] = cubicw(tx - (float)(k - 1));
        wy[k] = cubicw(ty - (float)(k - 1));
        int a = x0 + (k - 1); ix[k] = min(max(a, 0), 17);
        a = y0 + (k - 1);     iy[k] = min(max(a, 0), 17);
    }
    float acc[3];
    #pragma unroll
    for (int c = 0; c < 3; c++) {
        const float* src = f0 + (b * 3 + c) * 324;
        float a = 0.f;
        #pragma unroll
        for (int ky = 0; ky < 4; ky++) {
            float rowv = 0.f;
            #pragma unroll
            for (int kx = 0; kx < 4; kx++) rowv += wx[kx] * src[iy[ky] * 18 + ix[kx]];
            a += wy[ky] * rowv;
        }
        acc[c] = a;
    }
    hr4[idx] = make_float4(acc[0], acc[1], acc[2], 0.f);
}

// ---------------- fused JBU: scratch-free q-compute (per-lane A-frag) + fdot2 scores ----------------
__global__ __launch_bounds__(256, 4) void jbu_kernel(
    const float4* __restrict__ guid4,
    const __half* __restrict__ wsW1,
    const __half* __restrict__ wsB, const float* __restrict__ b2,
    const float4* __restrict__ hr4,
    float4* __restrict__ out4,
    float* __restrict__ outP,
    const float* __restrict__ temps,
    const float* __restrict__ sigmas,
    int stage)
{
    __shared__ __align__(16) char smem[SQ_B + TPIX * 16];  // 38784 B
    float4* sq = (float4*)smem;                 // q tile f16 chunk-planar [4][CS]
    float4* sh = (float4*)(smem + SQ_B);        // hr tile (3ch + pad)

    const int tx = threadIdx.x, ty = threadIdx.y;
    const int tid = ty * TILE + tx;
    const int b = blockIdx.z;
    const int h0 = blockIdx.y * TILE, w0 = blockIdx.x * TILE;

    // ---- stage hr tile ----
    const bool interior = (h0 >= RAD) && (h0 + TILE + RAD <= GHH) &&
                          (w0 >= RAD) && (w0 + TILE + RAD <= GWW);
    if (interior) {
        const float4* hb = hr4 + (size_t)b * HW + (size_t)(h0 - RAD) * GWW + (w0 - RAD);
        for (int i = tid; i < TPIX; i += 256) {
            int r = i / TP, cx = i % TP;
            sh[i] = hb[(size_t)r * GWW + cx];
        }
    } else {
        for (int i = tid; i < TPIX; i += 256) {
            int r = i / TP, cx = i % TP;
            int gh = refl(h0 - RAD + r);
            int gw = refl(w0 - RAD + cx);
            sh[i] = hr4[(size_t)b * HW + (size_t)gh * GWW + gw];
        }
    }

    // ---- phase 0: q tile, scratch-free. Lane (kq,n0) computes its OWN A-fragment
    //      (8 channels kq*8..kq*8+7 of pixel base+tt*16+n0) directly from guid. ----
    const int w = tid >> 6, l = tid & 63;
    const int n0 = l & 15, kq = l >> 4;
    const v8h* Bp = (const v8h*)(wsB + ((size_t)stage * 64 + l) * 16);
    const v8h B0 = Bp[0], B1 = Bp[1];
    const float bias0 = b2[n0], bias1 = b2[n0 + 16];
    union { _Float16 h[32]; float4 f4[4]; } W1;
    {
        const float4* wp = (const float4*)(wsW1 + stage * 128 + kq * 32);
        W1.f4[0] = wp[0]; W1.f4[1] = wp[1]; W1.f4[2] = wp[2]; W1.f4[3] = wp[3];
    }

    #pragma unroll 1
    for (int r2 = 0; r2 < 2; r2++) {
        #pragma unroll
        for (int tt = 0; tt < 4; tt++) {
            int base = r2 * 256 + w * 64 + tt * 16;
            int p = base + n0;
            int pc = min(p, TPIX - 1);
            int rr = pc / TP, cc = pc - rr * TP;
            int gh = refl(h0 - RAD + rr), gw = refl(w0 - RAD + cc);
            float4 g = guid4[(size_t)b * HW + (size_t)gh * GWW + gw];
            union { _Float16 h[8]; v8h v; } A;
            #pragma unroll
            for (int j = 0; j < 8; j++) {
                float vv = fmaf((float)W1.h[j * 4], g.x,
                           fmaf((float)W1.h[j * 4 + 1], g.y,
                           fmaf((float)W1.h[j * 4 + 2], g.z, (float)W1.h[j * 4 + 3])));
                A.h[j] = (_Float16)gelu_fast(vv);
            }
            v4f D0 = {0.f, 0.f, 0.f, 0.f}, D1 = {0.f, 0.f, 0.f, 0.f};
            D0 = __builtin_amdgcn_mfma_f32_16x16x32_f16(A.v, B0, D0, 0, 0, 0);
            D1 = __builtin_amdgcn_mfma_f32_16x16x32_f16(A.v, B1, D1, 0, 0, 0);
            #pragma unroll
            for (int r = 0; r < 4; r++) {
                int gpx = base + 4 * kq + r;   // C/D row = pixel (verified mapping)
                if (gpx < TPIX) {
                    *(_Float16*)(smem + ((n0 >> 3) * CS + gpx) * 16 + (n0 & 7) * 2)
                        = (_Float16)(D0[r] + bias0);
                    *(_Float16*)(smem + (((n0 >> 3) + 2) * CS + gpx) * 16 + (n0 & 7) * 2)
                        = (_Float16)(D1[r] + bias1);
                }
            }
        }
    }
    __syncthreads();   // sq + sh ready

    // ---- phase 1: scores (proven fdot2 structure, 1 px/thread) ----
    int ci = (ty + RAD) * TP + tx + RAD;
    float4 c0 = sq[ci], c1 = sq[CS + ci], c2 = sq[2 * CS + ci], c3 = sq[3 * CS + ci];

    float s[NPTS];
    int p = 0;
    #pragma unroll
    for (int di = 0; di < DIAM; di++) {
        int rb = (ty + di) * TP + tx;
        #pragma unroll
        for (int dj = 0; dj < DIAM; dj++, p++) {
            int ni = rb + dj;
            float acc = dot16(c0, sq[ni], 0.f);
            acc = dot16(c1, sq[CS + ni], acc);
            acc = dot16(c2, sq[2 * CS + ni], acc);
            acc = dot16(c3, sq[3 * CS + ni], acc);
            s[p] = acc;
        }
    }

    // ---- softmax * spatial, renormalize ----
    float t = __expf(temps[stage]);
    t = fminf(fmaxf(t, 1e-4f), 1e4f);
    float sig = sigmas[stage];
    float inv2s2 = 1.f / (2.f * sig * sig);
    float m = -1e30f;
    #pragma unroll
    for (int p2 = 0; p2 < NPTS; p2++) { s[p2] *= t; m = fmaxf(m, s[p2]); }
    float den = 0.f;
    #pragma unroll
    for (int p2 = 0; p2 < NPTS; p2++) { s[p2] = __expf(s[p2] - m); den += s[p2]; }
    float rden = 1.f / den;
    float ksum = 0.f;
    #pragma unroll
    for (int p2 = 0; p2 < NPTS; p2++) {
        int di = p2 / 7, dj = p2 % 7;
        float dy = (float)(di - 3) * (1.f / 3.f);
        float dx = (float)(dj - 3) * (1.f / 3.f);
        float spat = __expf(-(dy * dy + dx * dx) * inv2s2);
        s[p2] = s[p2] * rden * spat;
        ksum += s[p2];
    }
    float rk = 1.f / fmaxf(ksum, 1e-7f);

    // ---- adaptive conv from sh ----
    float o0 = 0.f, o1 = 0.f, o2 = 0.f;
    p = 0;
    #pragma unroll
    for (int di = 0; di < DIAM; di++) {
        int rb = (ty + di) * TP + tx;
        #pragma unroll
        for (int dj = 0; dj < DIAM; dj++, p++) {
            float4 hv = sh[rb + dj];
            float kp = s[p] * rk;
            o0 += kp * hv.x;
            o1 += kp * hv.y;
            o2 += kp * hv.z;
        }
    }
    if (stage < 3) {
        out4[(size_t)b * HW + (size_t)(h0 + ty) * GWW + (w0 + tx)] = make_float4(o0, o1, o2, 0.f);
    } else {
        size_t obase = (size_t)b * 3 * HW + (size_t)(h0 + ty) * GWW + (w0 + tx);
        outP[obase]          = o0;
        outP[obase + HW]     = o1;
        outP[obase + 2 * HW] = o2;
    }
}

extern "C" void kernel_launch(void* const* d_in, const int* in_sizes, int n_in,
                              void* d_out, int out_size, void* d_ws, size_t ws_size,
                              hipStream_t stream) {
    const float* x      = (const float*)d_in[0];
    const float* guid   = (const float*)d_in[1];
    const float* lw     = (const float*)d_in[2];
    const float* lb     = (const float*)d_in[3];
    const float* w1s    = (const float*)d_in[4];
    const float* b1s    = (const float*)d_in[5];
    const float* w2s    = (const float*)d_in[6];
    const float* b2s    = (const float*)d_in[7];
    const float* temps  = (const float*)d_in[8];
    const float* sigmas = (const float*)d_in[9];

    char* ws = (char*)d_ws;
    const size_t P4_BYTES = (size_t)BATCH * HW * sizeof(float4);      // 6,422,528
    float4* guid4 = (float4*)ws;
    float4* hr4A  = (float4*)(ws + P4_BYTES);
    float4* hr4B  = (float4*)(ws + 2 * P4_BYTES);
    float*  f0    = (float*)(ws + 3 * P4_BYTES);                      // 31,104 B
    __half* wsB   = (__half*)(ws + 3 * P4_BYTES + 31104);             //  8,192 B
    __half* wsW1  = (__half*)(ws + 3 * P4_BYTES + 31104 + 8192);      //  1,024 B

    linear_prep_kernel<<<1946 + 1568, 256, 0, stream>>>(
        x, lw, lb, f0, w2s, wsB, w1s, b1s, wsW1, guid, guid4);
    bicubic_kernel<<<(BATCH * HW + 255) / 256, 256, 0, stream>>>(f0, hr4A);

    dim3 jgrid(14, 14, BATCH), jblock(16, 16);
    const float4* hins[4]  = { hr4A, hr4B, hr4A, hr4B };
    float4*       fouts[4] = { hr4B, hr4A, hr4B, nullptr };
    for (int s = 0; s < 4; s++) {
        jbu_kernel<<<jgrid, jblock, 0, stream>>>(
            guid4, wsW1, wsB, b2s + s * 32,
            hins[s], fouts[s], (s == 3) ? (float*)d_out : nullptr,
            temps, sigmas, s);
    }
}